// Round 1
// baseline (1059.737 us; speedup 1.0000x reference)
//
#include <hip/hip_runtime.h>
#include <hip/hip_bf16.h>

#define B_ 128
#define H_ 512
#define S_ 2048
#define ST 64          // s-tile per pass-1 block
#define NP (S_/ST)     // 32 partials per batch

typedef short  bf16x8  __attribute__((ext_vector_type(8)));
typedef float  floatx4 __attribute__((ext_vector_type(4)));
typedef short  short4v __attribute__((ext_vector_type(4)));

// 2*log2(e): tanh(x) = 1 - 2*rcp(exp2(KT*x)+1)  (saturates correctly at +-inf,
// no clamp needed: exp2->inf => rcp->0 => 1; exp2->0 => rcp(1)=1 => -1)
#define KT_TANH 2.8853900817779268f

__device__ __forceinline__ unsigned short f2bf(float f){
  unsigned u = __float_as_uint(f);
  unsigned r = (u + 0x7fffu + ((u >> 16) & 1u)) >> 16;   // RNE
  return (unsigned short)r;
}
__device__ __forceinline__ float bf2f(unsigned short h){
  return __uint_as_float(((unsigned)h) << 16);
}
// r = rcp(exp2(a)+1) ; tanh-form helper: tanh = 1 - 2r
__device__ __forceinline__ float tanh_r(float a){
  float e = __builtin_amdgcn_exp2f(a);
  return __builtin_amdgcn_rcpf(e + 1.f);
}
// XOR swizzle: row-stride 512 elems (no pad); 16B chunk c of row s lives at
// phys = (c & 56) | ((c ^ s) & 7). Conflict-free for row-writes, frag-reads,
// and full-row readback (bijective in c for fixed s).
__device__ __forceinline__ int swz(int s, int c){
  return (c & 56) | ((c ^ s) & 7);
}

// ---------------- k0: W_att fp32 -> bf16 ----------------
__global__ __launch_bounds__(256) void k_convW(const float* __restrict__ W,
                                               unsigned short* __restrict__ Wb){
  int i = (blockIdx.x * 256 + threadIdx.x) * 4;
  float4 v = *(const float4*)(W + i);
  short4v o;
  o[0] = (short)f2bf(v.x); o[1] = (short)f2bf(v.y);
  o[2] = (short)f2bf(v.z); o[3] = (short)f2bf(v.w);
  *(short4v*)(Wb + i) = o;
}

// ---------------- k_pass1: stage + scores GEMM + tanh.v + partial softmax ---
// grid = B*NP blocks of 512 (8 waves). Wave w owns h-rows [w*64, w*64+64).
// No hT materialization: k_probs re-reads fp32 hidden (same total HBM bytes,
// one fewer phase here, and fp32-accurate final tanh).
__global__ __launch_bounds__(512, 4) void k_pass1(
    const float* __restrict__ hidden, const float* __restrict__ v_att,
    const unsigned short* __restrict__ Wb,
    float* __restrict__ part_m, float* __restrict__ part_z,
    float* __restrict__ part_ctx)
{
  // pctx (16 KiB, fp32 cross-wave ctx reduce) aliases Bs: Bs is fully consumed
  // before pctx is written (barrier-separated).
  union __align__(16) SMem {
    unsigned short Bs[ST * 512];   // 64 KiB, swizzled bf16 [s][k]
    float pctx[8 * H_];            // 16 KiB
  };
  __shared__ SMem sm;
  __shared__ float vatt[H_];
  __shared__ float twav[8][ST];
  __shared__ float ts[ST];
  __shared__ float es[ST];
  __shared__ float sva_sh;

  const int tid = threadIdx.x;
  const int w = tid >> 6, l = tid & 63;
  const int p = blockIdx.x & (NP - 1);
  const int b = blockIdx.x >> 5;          // NP == 32
  const int s0 = p * ST;

  vatt[tid] = v_att[tid];

  // Stage hidden[b, :, s0:s0+64] -> bf16 LDS [s][k] (swizzled).
  // Thread: row s=l, 8 chunks c = w + it*8; each chunk = 8 h, stride-S gather
  // (coalesced 256B across the wave per h-row). Nontemporal: keep Wb L2-hot.
  {
    const float* src0 = hidden + ((size_t)b * H_) * S_ + s0 + l;
    #pragma unroll
    for (int it = 0; it < 8; ++it){
      const int c = w + it * 8;
      const float* src = src0 + (size_t)(c * 8) * S_;
      bf16x8 pk;
      #pragma unroll
      for (int j = 0; j < 8; ++j)
        pk[j] = (short)f2bf(__builtin_nontemporal_load(src + (size_t)j * S_));
      *(bf16x8*)(&sm.Bs[l * 512 + swz(l, c) * 8]) = pk;
    }
  }
  __syncthreads();

  // SVA = sum_h v_att[h], once per block (wave 0). Consumed after twav barrier.
  if (w == 0){
    float sv = 0.f;
    #pragma unroll
    for (int k = 0; k < 8; ++k) sv += vatt[l + 64 * k];
    sv += __shfl_xor(sv, 1);  sv += __shfl_xor(sv, 2);
    sv += __shfl_xor(sv, 4);  sv += __shfl_xor(sv, 8);
    sv += __shfl_xor(sv, 16); sv += __shfl_xor(sv, 32);
    if (l == 0) sva_sh = sv;
  }

  const int quad = l >> 4, l16 = l & 15;
  float tacc[4] = {0.f, 0.f, 0.f, 0.f};   // accumulates sum_h v[h]*r[h][s]

  {
    floatx4 acc[4][4];
    #pragma unroll
    for (int ti = 0; ti < 4; ++ti)
      #pragma unroll
      for (int ss = 0; ss < 4; ++ss){
        floatx4 z4 = {0.f, 0.f, 0.f, 0.f};
        acc[ti][ss] = z4;
      }

    for (int k0 = 0; k0 < H_; k0 += 32){
      bf16x8 a[4];
      #pragma unroll
      for (int ti = 0; ti < 4; ++ti)
        a[ti] = *(const bf16x8*)(Wb + ((w * 4 + ti) * 16 + l16) * H_ + k0 + quad * 8);
      bf16x8 bb[4];
      #pragma unroll
      for (int ss = 0; ss < 4; ++ss){
        const int c = (k0 >> 3) + quad;
        bb[ss] = *(const bf16x8*)(&sm.Bs[(ss * 16 + l16) * 512 + swz(l16, c) * 8]);
      }
      #pragma unroll
      for (int ti = 0; ti < 4; ++ti)
        #pragma unroll
        for (int ss = 0; ss < 4; ++ss)
          acc[ti][ss] = __builtin_amdgcn_mfma_f32_16x16x32_bf16(a[ti], bb[ss], acc[ti][ss], 0, 0, 0);
    }

    // t[s] = SVA - 2*sum_h v[h]*r ; accumulate only sum v*r here (4-op tanh).
    // C layout col=l16 (s), row=quad*4+r.
    #pragma unroll
    for (int ti = 0; ti < 4; ++ti){
      const int hbase = (w * 4 + ti) * 16 + quad * 4;
      #pragma unroll
      for (int r = 0; r < 4; ++r){
        float va = vatt[hbase + r];
        #pragma unroll
        for (int ss = 0; ss < 4; ++ss)
          tacc[ss] = fmaf(va, tanh_r(acc[ti][ss][r] * KT_TANH), tacc[ss]);
      }
    }
  }

  #pragma unroll
  for (int ss = 0; ss < 4; ++ss){
    tacc[ss] += __shfl_xor(tacc[ss], 16);
    tacc[ss] += __shfl_xor(tacc[ss], 32);
  }
  if (l < 16){
    #pragma unroll
    for (int ss = 0; ss < 4; ++ss) twav[w][ss * 16 + l] = tacc[ss];
  }
  __syncthreads();
  if (tid < ST){
    float a = 0.f;
    #pragma unroll
    for (int ww = 0; ww < 8; ++ww) a += twav[ww][tid];
    ts[tid] = sva_sh - 2.f * a;
  }
  __syncthreads();

  float m = -1e30f;
  for (int s = 0; s < ST; ++s) m = fmaxf(m, ts[s]);
  if (tid < ST) es[tid] = __expf(ts[tid] - m);
  __syncthreads();
  float z = 0.f;
  for (int s = 0; s < ST; ++s) z += es[s];

  const int pidx = b * NP + p;
  if (tid == 0){ part_m[pidx] = m; part_z[pidx] = z; }

  // Partial (unnormalized) context, vectorized:
  // phase R: wave w consumes rows [w*8, w*8+8), lane l -> chunk l (b128,
  //          conflict-free row readback), accumulating 8 h-values in regs.
  float a8[8] = {0.f,0.f,0.f,0.f,0.f,0.f,0.f,0.f};
  #pragma unroll
  for (int j = 0; j < 8; ++j){
    const int s = w * 8 + j;
    const float ez = es[s];                       // wave-uniform broadcast
    bf16x8 v = *(const bf16x8*)(&sm.Bs[s * 512 + swz(s, l) * 8]);
    #pragma unroll
    for (int e = 0; e < 8; ++e)
      a8[e] = fmaf(ez, bf2f((unsigned short)v[e]), a8[e]);
  }
  __syncthreads();               // all Bs reads done -> safe to alias
  // phase W: pctx[w][h], h = l*8+e (contiguous per lane -> conflict-free)
  {
    floatx4 lo = {a8[0], a8[1], a8[2], a8[3]};
    floatx4 hi = {a8[4], a8[5], a8[6], a8[7]};
    *(floatx4*)(&sm.pctx[w * H_ + l * 8])     = lo;
    *(floatx4*)(&sm.pctx[w * H_ + l * 8 + 4]) = hi;
  }
  __syncthreads();
  // phase F: h = tid; sum the 8 wave partials (stride H_ -> bank = tid%32, free)
  {
    float a = 0.f;
    #pragma unroll
    for (int ww = 0; ww < 8; ++ww) a += sm.pctx[ww * H_ + tid];
    part_ctx[(size_t)pidx * H_ + tid] = a;
  }
}

// ---------------- k2: combine partials -> context -> 2-layer MLP ------------
__global__ __launch_bounds__(256) void k_mlp(
    const float* __restrict__ part_m, const float* __restrict__ part_z,
    const float* __restrict__ part_ctx,
    const float* __restrict__ fc1_w, const float* __restrict__ fc1_b,
    const float* __restrict__ fc2_w, const float* __restrict__ fc2_b,
    float* __restrict__ out2)
{
  __shared__ float ctx[H_];
  __shared__ float h1[H_];
  __shared__ float wp[NP];
  const int b = blockIdx.x, tid = threadIdx.x;

  float m = -1e30f;
  for (int pp = 0; pp < NP; ++pp) m = fmaxf(m, part_m[b * NP + pp]);
  if (tid < NP) wp[tid] = __expf(part_m[b * NP + tid] - m);
  __syncthreads();
  float z = 0.f;
  for (int pp = 0; pp < NP; ++pp) z += wp[pp] * part_z[b * NP + pp];
  float invz = 1.f / z;

  for (int h = tid; h < H_; h += 256){
    float a = 0.f;
    for (int pp = 0; pp < NP; ++pp) a += wp[pp] * part_ctx[(size_t)(b * NP + pp) * H_ + h];
    ctx[h] = a * invz;
  }
  __syncthreads();

  for (int i = tid; i < H_; i += 256){
    const float4* row = (const float4*)(fc1_w + (size_t)i * H_);
    float4 s4 = {0.f, 0.f, 0.f, 0.f};
    for (int j = 0; j < H_ / 4; ++j){
      float4 wv = row[j];
      s4.x += wv.x * ctx[4 * j];     s4.y += wv.y * ctx[4 * j + 1];
      s4.z += wv.z * ctx[4 * j + 2]; s4.w += wv.w * ctx[4 * j + 3];
    }
    h1[i] = fmaxf(fc1_b[i] + s4.x + s4.y + s4.z + s4.w, 0.f);
  }
  __syncthreads();

  for (int i = tid; i < H_; i += 256){
    const float4* row = (const float4*)(fc2_w + (size_t)i * H_);
    float4 s4 = {0.f, 0.f, 0.f, 0.f};
    for (int j = 0; j < H_ / 4; ++j){
      float4 wv = row[j];
      s4.x += wv.x * h1[4 * j];     s4.y += wv.y * h1[4 * j + 1];
      s4.z += wv.z * h1[4 * j + 2]; s4.w += wv.w * h1[4 * j + 3];
    }
    out2[(size_t)b * H_ + i] = fmaxf(fc2_b[i] + s4.x + s4.y + s4.z + s4.w, 0.f);
  }
}

// ---------------- k_probs: fp32 hidden, lane-owns-s, no cross-lane reduce ---
// probs[b,s] = SVP - 2 * sum_h vp[h]*rcp(exp2(KT*h + KT*o[h])+1)
__global__ __launch_bounds__(256) void k_probs(
    const float* __restrict__ hidden, const float* __restrict__ v_ptr,
    const float* __restrict__ out2, float* __restrict__ probs)
{
  __shared__ float vp[H_], ko[H_];
  __shared__ float svp_sh;
  const int b = blockIdx.y, c = blockIdx.x, tid = threadIdx.x;
  vp[tid]       = v_ptr[tid];
  vp[tid + 256] = v_ptr[tid + 256];
  ko[tid]       = KT_TANH * out2[(size_t)b * H_ + tid];
  ko[tid + 256] = KT_TANH * out2[(size_t)b * H_ + tid + 256];
  __syncthreads();
  if (tid < 64){
    float sv = 0.f;
    #pragma unroll
    for (int k = 0; k < 8; ++k) sv += vp[tid + 64 * k];
    sv += __shfl_xor(sv, 1);  sv += __shfl_xor(sv, 2);
    sv += __shfl_xor(sv, 4);  sv += __shfl_xor(sv, 8);
    sv += __shfl_xor(sv, 16); sv += __shfl_xor(sv, 32);
    if (tid == 0) svp_sh = sv;
  }
  __syncthreads();

  const int s = c * 512 + tid * 2;
  const float* base = hidden + (size_t)b * H_ * S_ + s;
  float a0 = 0.f, a1 = 0.f;
  const float kt = KT_TANH;
  #pragma unroll 8
  for (int h = 0; h < H_; ++h){
    float2 hv = *(const float2*)(base + (size_t)h * S_);
    float wv = vp[h], o = ko[h];
    a0 = fmaf(wv, tanh_r(fmaf(kt, hv.x, o)), a0);
    a1 = fmaf(wv, tanh_r(fmaf(kt, hv.y, o)), a1);
  }
  float svp = svp_sh;
  float2 r2 = { svp - 2.f * a0, svp - 2.f * a1 };
  *(float2*)(probs + (size_t)b * S_ + s) = r2;
}

// ---------------- launcher ----------------
extern "C" void kernel_launch(void* const* d_in, const int* in_sizes, int n_in,
                              void* d_out, int out_size, void* d_ws, size_t ws_size,
                              hipStream_t stream)
{
  const float* hidden = (const float*)d_in[0];
  const float* v_att  = (const float*)d_in[1];
  const float* W_att  = (const float*)d_in[2];
  const float* v_ptr  = (const float*)d_in[3];
  const float* fc1_w  = (const float*)d_in[4];
  const float* fc1_b  = (const float*)d_in[5];
  const float* fc2_w  = (const float*)d_in[6];
  const float* fc2_b  = (const float*)d_in[7];
  float* probs = (float*)d_out;

  char* ws = (char*)d_ws;
  unsigned short* Wb = (unsigned short*)ws;                        // 512 KiB
  float* part_m   = (float*)(ws + (512u<<10));                     // 16 KiB
  float* part_z   = (float*)(ws + (512u<<10) + (16u<<10));         // 16 KiB
  float* part_ctx = (float*)(ws + (512u<<10) + (32u<<10));         // 8 MiB
  float* out2     = (float*)(ws + (512u<<10) + (32u<<10) + (8u<<20)); // 256 KiB

  hipLaunchKernelGGL(k_convW, dim3(256), dim3(256), 0, stream, W_att, Wb);
  hipLaunchKernelGGL(k_pass1, dim3(B_ * NP), dim3(512), 0, stream,
                     hidden, v_att, Wb, part_m, part_z, part_ctx);
  hipLaunchKernelGGL(k_mlp, dim3(B_), dim3(256), 0, stream,
                     part_m, part_z, part_ctx, fc1_w, fc1_b, fc2_w, fc2_b, out2);
  hipLaunchKernelGGL(k_probs, dim3(S_ / 512, B_), dim3(256), 0, stream,
                     hidden, v_ptr, out2, probs);
}